// Round 5
// baseline (698.869 us; speedup 1.0000x reference)
//
#include <hip/hip_runtime.h>
#include <hip/hip_bf16.h>
#include <cstdint>

// Problem constants
// B=128, P=168, M=8, HIDC=50, HIDR=50, HIDS=5, CK=6, SKIP=24, HW=24
// O = P*HIDC*CK = 50400, Kdim = P*M = 1344, L = 163, PT = 6

typedef __attribute__((ext_vector_type(8))) short short8;   // 8 bf16 (4 VGPRs)
typedef __attribute__((ext_vector_type(4))) float f32x4;    // MFMA acc

__device__ __forceinline__ unsigned short bf16rn(float f) {
    unsigned u = __float_as_uint(f);
    return (unsigned short)((u + 0x7FFFu + ((u >> 16) & 1u)) >> 16);
}
__device__ __forceinline__ unsigned pk2(float a, float b) {
    return ((unsigned)bf16rn(b) << 16) | (unsigned)bf16rn(a);
}
__device__ __forceinline__ uint4 pack8(float4 f0, float4 f1) {
    uint4 u;
    u.x = pk2(f0.x, f0.y); u.y = pk2(f0.z, f0.w);
    u.z = pk2(f1.x, f1.y); u.w = pk2(f1.z, f1.w);
    return u;
}
__device__ __forceinline__ float bf2f(unsigned short u) {
    return __uint_as_float((unsigned)u << 16);
}
__device__ __forceinline__ float sigmf(float x) { return 1.f / (1.f + __expf(-x)); }
__device__ __forceinline__ float tanhf_(float x) { return 1.f - 2.f / (__expf(2.f * x) + 1.f); }

// ---------------------------------------------------------------------------
// K0: one-shot fp32 -> bf16 convert of x (172,032 elems) so K1's A staging is
// a raw 16B load (no per-block re-pack).
// ---------------------------------------------------------------------------
__global__ __launch_bounds__(256)
void k0_cvt(const float* __restrict__ x, unsigned short* __restrict__ xb) {
    int i = (blockIdx.x * 256 + threadIdx.x) * 8;
    float4 f0 = *reinterpret_cast<const float4*>(x + i);
    float4 f1 = *reinterpret_cast<const float4*>(x + i + 4);
    *reinterpret_cast<uint4*>(xb + i) = pack8(f0, f1);
}

// ---------------------------------------------------------------------------
// K1: c[b][o] = relu(xbf16 @ wf^T + conv_b), stored bf16. M=128,N=50400,K=1344.
// Tile 128x48, BK=64, grid 1050 (~4.1 blocks/CU), __launch_bounds__(256,4).
// Register-prefetch pipeline: loads for tile k+1 issue right after the first
// barrier; A is bf16 (straight uint4 copy), B is fp32 -> packed in regs.
// ---------------------------------------------------------------------------
__global__ __launch_bounds__(256, 4)
void k1_conv_gemm(const unsigned short* __restrict__ xb, const float* __restrict__ w,
                  const float* __restrict__ bias, unsigned short* __restrict__ c) {
    __shared__ uint4 a_lds[8 * 129];  // A: [ks][row], 128 rows pad->129
    __shared__ uint4 b_lds[8 * 49];   // B: [ks][row], 48 rows pad->49
    const int tid  = threadIdx.x;
    const int n0   = blockIdx.x * 48;
    const int wave = tid >> 6, lane = tid & 63;
    const int quad = lane >> 4, m16 = lane & 15;

    f32x4 acc[2][3];
#pragma unroll
    for (int i = 0; i < 2; ++i)
#pragma unroll
        for (int j = 0; j < 3; ++j) acc[i][j] = (f32x4){0.f, 0.f, 0.f, 0.f};

    const int arow = tid >> 3, aks = tid & 7;   // A packet (row+32i, ks)
    const int brow1 = (tid + 256) >> 3;         // B packet for threads<128

    uint4  pa[4];
    float4 pb0[2], pb1[2];

    auto issue = [&](int kb) {
#pragma unroll
        for (int i = 0; i < 4; ++i) {
            const unsigned short* gp = xb + (arow + 32 * i) * 1344 + kb + aks * 8;
            pa[i] = *reinterpret_cast<const uint4*>(gp);
        }
        {
            const float* gp = w + (size_t)(n0 + arow) * 1344 + kb + aks * 8;
            pb0[0] = *reinterpret_cast<const float4*>(gp);
            pb0[1] = *reinterpret_cast<const float4*>(gp + 4);
        }
        if (tid < 128) {  // wave-uniform
            const float* gp = w + (size_t)(n0 + brow1) * 1344 + kb + aks * 8;
            pb1[0] = *reinterpret_cast<const float4*>(gp);
            pb1[1] = *reinterpret_cast<const float4*>(gp + 4);
        }
    };

    issue(0);
    for (int kb = 0; kb < 1344; kb += 64) {
        // commit prefetched regs -> LDS
#pragma unroll
        for (int i = 0; i < 4; ++i)
            a_lds[aks * 129 + arow + 32 * i] = pa[i];
        b_lds[aks * 49 + arow] = pack8(pb0[0], pb0[1]);
        if (tid < 128)
            b_lds[aks * 49 + brow1] = pack8(pb1[0], pb1[1]);
        __syncthreads();
        if (kb + 64 < 1344) issue(kb + 64);  // overlap with MFMA below
#pragma unroll
        for (int half = 0; half < 2; ++half) {
            const int kp = half * 4 + quad;
            short8 af[2], bfr[3];
#pragma unroll
            for (int rt = 0; rt < 2; ++rt)
                af[rt] = ((const short8*)a_lds)[kp * 129 + wave * 32 + rt * 16 + m16];
#pragma unroll
            for (int ct = 0; ct < 3; ++ct)
                bfr[ct] = ((const short8*)b_lds)[kp * 49 + ct * 16 + m16];
#pragma unroll
            for (int rt = 0; rt < 2; ++rt)
#pragma unroll
                for (int ct = 0; ct < 3; ++ct)
                    acc[rt][ct] = __builtin_amdgcn_mfma_f32_16x16x32_bf16(
                        af[rt], bfr[ct], acc[rt][ct], 0, 0, 0);
        }
        __syncthreads();
    }
    // epilogue: bias + relu + bf16 store. D map: row=(lane>>4)*4+r, col=lane&15
#pragma unroll
    for (int ct = 0; ct < 3; ++ct) {
        int col = n0 + ct * 16 + m16;
        float bv = bias[col];
#pragma unroll
        for (int rt = 0; rt < 2; ++rt) {
#pragma unroll
            for (int r = 0; r < 4; ++r) {
                int grow = wave * 32 + rt * 16 + quad * 4 + r;  // b
                float v = acc[rt][ct][r] + bv;
                v = fmaxf(v, 0.f);
                c[(size_t)grow * 50400 + col] = bf16rn(v);
            }
        }
    }
}

// ---------------------------------------------------------------------------
// K2f: fused diag-sum + gi1 + gi2. One block per batch element b.
// res1 row [t][hc] lives only in LDS. Threads 0..149 own gi1 column cc with the
// w-row in VGPRs; x-row read as LDS broadcasts. Wave 3 computes gi2.
// ---------------------------------------------------------------------------
__global__ __launch_bounds__(256)
void k2f(const unsigned short* __restrict__ c,
         const float* __restrict__ g1_wih, const float* __restrict__ g1_bih,
         const float* __restrict__ gs_wih, const float* __restrict__ gs_bih,
         float* __restrict__ gi1, float* __restrict__ gi2) {
    __shared__ float xl[163 * 52];   // res1 [t][hc], pad 52 (16B-aligned rows)
    __shared__ float wl1[150 * 52];  // g1_wih padded
    __shared__ float wl2[15 * 52];   // gs_wih padded
    __shared__ float bl2[15];
    const int b = blockIdx.x;
    const int tid = threadIdx.x;
    const unsigned short* cb = c + (size_t)b * 50400;

    for (int i = tid; i < 7500; i += 256) {
        int r = i / 50, j = i - r * 50;
        wl1[r * 52 + j] = g1_wih[i];
    }
    for (int i = tid; i < 750; i += 256) {
        int r = i / 50, j = i - r * 50;
        wl2[r * 52 + j] = gs_wih[i];
    }
    if (tid < 15) bl2[tid] = gs_bih[tid];
    for (int idx = tid; idx < 8150; idx += 256) {
        int hc = idx / 163, t = idx - hc * 163;
        int base = hc * 1008 + t;
        float s = 0.f;
#pragma unroll
        for (int k = 0; k < 6; ++k) s += bf2f(cb[base + 169 * k]);
        xl[t * 52 + hc] = s;
    }
    __syncthreads();

    if (tid < 150) {
        const int cc = tid;
        float wr[50];
#pragma unroll
        for (int j = 0; j < 48; j += 4)
            *reinterpret_cast<float4*>(&wr[j]) =
                *reinterpret_cast<const float4*>(&wl1[cc * 52 + j]);
        wr[48] = wl1[cc * 52 + 48]; wr[49] = wl1[cc * 52 + 49];
        const float bv = g1_bih[cc];
        float* gout = gi1 + (size_t)b * 150 + cc;
        for (int t = 0; t < 163; ++t) {
            const float* xp = &xl[t * 52];
            float4 a = {0.f, 0.f, 0.f, 0.f};
#pragma unroll
            for (int j = 0; j < 48; j += 4) {
                float4 xv = *reinterpret_cast<const float4*>(xp + j);
                a.x += xv.x * wr[j + 0]; a.y += xv.y * wr[j + 1];
                a.z += xv.z * wr[j + 2]; a.w += xv.w * wr[j + 3];
            }
            float acc = bv + xp[48] * wr[48] + xp[49] * wr[49]
                      + (a.x + a.y) + (a.z + a.w);
            gout[(size_t)t * 128 * 150] = acc;
        }
    } else if (tid >= 192) {
        for (int e = tid - 192; e < 2160; e += 64) {
            int rr = e / 15, cc = e - rr * 15;
            int pt = rr / 24, sk = rr - pt * 24;
            int t = 19 + pt * 24 + sk;
            const float* xp = &xl[t * 52];
            const float* wp = &wl2[cc * 52];
            float4 a = {0.f, 0.f, 0.f, 0.f};
#pragma unroll
            for (int j = 0; j < 48; j += 4) {
                float4 xv = *reinterpret_cast<const float4*>(xp + j);
                float4 wv = *reinterpret_cast<const float4*>(wp + j);
                a.x += xv.x * wv.x; a.y += xv.y * wv.y;
                a.z += xv.z * wv.z; a.w += xv.w * wv.w;
            }
            float acc = bl2[cc] + xp[48] * wp[48] + xp[49] * wp[49]
                      + (a.x + a.y) + (a.z + a.w);
            gi2[(size_t)(pt * 3072 + b * 24 + sk) * 15 + cc] = acc;
        }
    }
}

// ---------------------------------------------------------------------------
// K4: GRU1 recurrence + fused gru2 + final linear/highway/sigmoid.
// One block (1 wave) per batch element. Lane l<50 owns hidden unit l with
// w_hh rows in VGPRs; double-buffered h in LDS, one barrier per step, gi
// prefetched. Tail: lanes 0..23 run gru2 for b's 24 sequences; lanes 0..7
// produce the 8 outputs. All deps block-local (no r1/hs round-trip).
// ---------------------------------------------------------------------------
__global__ __launch_bounds__(64)
void k4_gru1(const float* __restrict__ gi1, const float* __restrict__ whh,
             const float* __restrict__ bhh, const float* __restrict__ gi2,
             const float* __restrict__ gs_whh, const float* __restrict__ gs_bhh,
             const float* __restrict__ l1w, const float* __restrict__ l1b,
             const float* __restrict__ x, const float* __restrict__ hww,
             const float* __restrict__ hwb, float* __restrict__ out) {
    __shared__ float wl[7500];
    __shared__ float g2[90];   // gs_whh(75) + gs_bhh(15)
    __shared__ __align__(16) float hl[2][64];
    const int b = blockIdx.x;
    const int l = threadIdx.x;
    for (int idx = l; idx < 7500; idx += 64) wl[idx] = whh[idx];
    // stage gs weights: 75 + 15 floats over 64 lanes (strided! 64 < 75)
    for (int i = l; i < 75; i += 64) g2[i] = gs_whh[i];
    if (l < 15) g2[75 + l] = gs_bhh[l];
    hl[0][l] = 0.f;
    hl[1][l] = 0.f;
    __syncthreads();
    const int lc = (l < 50) ? l : 49;
    float wr[50], wz[50], wn[50];
#pragma unroll
    for (int j = 0; j < 50; ++j) {
        wr[j] = wl[lc * 50 + j];
        wz[j] = wl[(50 + lc) * 50 + j];
        wn[j] = wl[(100 + lc) * 50 + j];
    }
    const float bhr = bhh[lc], bhz = bhh[50 + lc], bhn = bhh[100 + lc];
    float hcur = 0.f;
    const float* gp = gi1 + (size_t)b * 150;   // t-stride = 128*150
    float gir = gp[lc], giz = gp[50 + lc], gin = gp[100 + lc];
    int p = 0;
    for (int t = 0; t < 163; ++t) {
        float ngir = 0.f, ngiz = 0.f, ngin = 0.f;
        if (t < 162) {
            const float* gq = gp + 150 * 128;
            ngir = gq[lc]; ngiz = gq[50 + lc]; ngin = gq[100 + lc];
        }
        const float* hp = hl[p];
        float ar = bhr, az = bhz, an = bhn;
#pragma unroll
        for (int j4 = 0; j4 < 12; ++j4) {
            float4 hv = *reinterpret_cast<const float4*>(hp + 4 * j4);
            ar += wr[4 * j4 + 0] * hv.x + wr[4 * j4 + 1] * hv.y +
                  wr[4 * j4 + 2] * hv.z + wr[4 * j4 + 3] * hv.w;
            az += wz[4 * j4 + 0] * hv.x + wz[4 * j4 + 1] * hv.y +
                  wz[4 * j4 + 2] * hv.z + wz[4 * j4 + 3] * hv.w;
            an += wn[4 * j4 + 0] * hv.x + wn[4 * j4 + 1] * hv.y +
                  wn[4 * j4 + 2] * hv.z + wn[4 * j4 + 3] * hv.w;
        }
        {
            float h48 = hp[48], h49 = hp[49];
            ar += wr[48] * h48 + wr[49] * h49;
            az += wz[48] * h48 + wz[49] * h49;
            an += wn[48] * h48 + wn[49] * h49;
        }
        float rg = sigmf(gir + ar);
        float zg = sigmf(giz + az);
        float ng = tanhf_(gin + rg * an);
        float hn = (1.f - zg) * ng + zg * hcur;
        hl[1 - p][l] = hn;
        __syncthreads();
        p ^= 1;
        hcur = hn;
        gir = ngir; giz = ngiz; gin = ngin;
        gp += 150 * 128;
    }
    // ---- fused tail ----
    if (l < 50) wl[l] = hcur;          // r1 block-local (wl's GRU role is done)
    __syncthreads();
    if (l < 24) {                      // gru2: sequence (b, sk=l), 6 steps
        float h[5] = {0.f, 0.f, 0.f, 0.f, 0.f};
        for (int pt = 0; pt < 6; ++pt) {
            const float* gq = gi2 + (size_t)(pt * 3072 + b * 24 + l) * 15;
            float gi[15];
#pragma unroll
            for (int i = 0; i < 15; ++i) gi[i] = gq[i];
            float gh[15];
#pragma unroll
            for (int i = 0; i < 15; ++i) {
                float s = g2[75 + i];
#pragma unroll
                for (int j = 0; j < 5; ++j) s += g2[i * 5 + j] * h[j];
                gh[i] = s;
            }
#pragma unroll
            for (int u = 0; u < 5; ++u) {
                float rg = sigmf(gi[u] + gh[u]);
                float zg = sigmf(gi[5 + u] + gh[5 + u]);
                float ng = tanhf_(gi[10 + u] + rg * gh[10 + u]);
                h[u] = (1.f - zg) * ng + zg * h[u];
            }
        }
#pragma unroll
        for (int u = 0; u < 5; ++u) wl[64 + l * 5 + u] = h[u];  // hs block-local
    }
    __syncthreads();
    if (l < 8) {
        const int m = l;
        float acc = l1b[m];
        const float* wrow = l1w + m * 170;
#pragma unroll
        for (int j = 0; j < 50; ++j) acc += wl[j] * wrow[j];
#pragma unroll
        for (int j = 0; j < 120; ++j) acc += wl[64 + j] * wrow[50 + j];
        float z = hwb[0];
        const float* xb2 = x + b * 1344 + 1152 + m;
#pragma unroll
        for (int wi = 0; wi < 24; ++wi) z += xb2[wi * 8] * hww[wi];
        out[b * 8 + m] = sigmf(acc + z);
    }
}

// ---------------------------------------------------------------------------
extern "C" void kernel_launch(void* const* d_in, const int* in_sizes, int n_in,
                              void* d_out, int out_size, void* d_ws, size_t ws_size,
                              hipStream_t stream) {
    const float* x      = (const float*)d_in[0];
    const float* conv_w = (const float*)d_in[1];
    const float* conv_b = (const float*)d_in[2];
    const float* g1_wih = (const float*)d_in[3];
    const float* g1_whh = (const float*)d_in[4];
    const float* g1_bih = (const float*)d_in[5];
    const float* g1_bhh = (const float*)d_in[6];
    const float* gs_wih = (const float*)d_in[7];
    const float* gs_whh = (const float*)d_in[8];
    const float* gs_bih = (const float*)d_in[9];
    const float* gs_bhh = (const float*)d_in[10];
    const float* l1_w   = (const float*)d_in[11];
    const float* l1_b   = (const float*)d_in[12];
    const float* hw_w   = (const float*)d_in[13];
    const float* hw_b   = (const float*)d_in[14];
    float* out = (float*)d_out;

    char* ws = (char*)d_ws;
    // ws layout (~27.3 MB total)
    unsigned short* c   = (unsigned short*)(ws);               // 12,902,400 B
    float* gi1          = (float*)(ws + 12902400);             // 12,518,400 B
    float* gi2          = (float*)(ws + 25420800);             //  1,105,920 B
    unsigned short* xbf = (unsigned short*)(ws + 26526720);    //    344,064 B

    hipLaunchKernelGGL(k0_cvt,       dim3(84),   dim3(256), 0, stream, x, xbf);
    hipLaunchKernelGGL(k1_conv_gemm, dim3(1050), dim3(256), 0, stream, xbf, conv_w, conv_b, c);
    hipLaunchKernelGGL(k2f,          dim3(128),  dim3(256), 0, stream, c, g1_wih, g1_bih,
                       gs_wih, gs_bih, gi1, gi2);
    hipLaunchKernelGGL(k4_gru1,      dim3(128),  dim3(64),  0, stream, gi1, g1_whh, g1_bhh,
                       gi2, gs_whh, gs_bhh, l1_w, l1_b, x, hw_w, hw_b, out);
}